// Round 1
// baseline (689.024 us; speedup 1.0000x reference)
//
#include <hip/hip_runtime.h>
#include <math.h>

// SparseAttention B=2 H=16 S=2048 D=128, window half=102 (205 cols).
// out = ctx [B,H,S,D] ++ probs [B,H,S,S] (fp32).
// Round 4: occupancy 2 -> 3 blocks/CU. Ps_t staged per 128-k half (18432 B
// instead of 36864 B), LDS 72448 -> 54016, __launch_bounds__(256,3).
// Phase structure / numerics unchanged from round 3.

namespace {
constexpr int Sc = 2048, Dc = 128;
constexpr int HALFW = 102;
constexpr float SCALE = 0.08838834764831845f;   // 1/sqrt(128)
constexpr int TQ  = 32;    // q rows per block
constexpr int CT  = 256;   // padded window cols
constexpr int KST = 136;   // bf16 row stride for Qs/Ks
constexpr int VST = 132;   // fp32 row stride for Vsf (16B-aligned, kp-spread)
constexpr int PTS = 36;    // fp32 stride of Ps_t rows (per k): 32 rows + 4 pad
// LDS layout (bytes)
constexpr int OFF_KBUF = 0;                      // 34816: Ks bf16 128xKST / Vsf fp32 64xVST
constexpr int OFF_PST  = 34816;                  // 18432: Ps_t [128][36] fp32 (one 128-k half)
constexpr int OFF_QS   = 34816;                  // Qs bf16 32xKST overlay (dead before Ps_t)
constexpr int OFF_RED  = 34816 + 18432;          // red[32][4] + rowM[32] + rowSinv[32]
constexpr int LDS_TOTAL = OFF_RED + 512 + 128 + 128;   // 54016 B -> 3 blocks/CU
}

typedef __bf16 bf16x8 __attribute__((ext_vector_type(8)));
typedef float  f32x16 __attribute__((ext_vector_type(16)));
typedef float  fx4    __attribute__((ext_vector_type(4)));

__device__ __forceinline__ unsigned short f2bf(float f) {
    unsigned u = __float_as_uint(f);
    u += 0x7fffu + ((u >> 16) & 1u);     // round-to-nearest-even
    return (unsigned short)(u >> 16);
}

__global__ __launch_bounds__(256, 3) void sparse_attn_mfma(
    const float* __restrict__ Q, const float* __restrict__ K,
    const float* __restrict__ V, float* __restrict__ ctx,
    float* __restrict__ probs)
{
    __shared__ __align__(16) unsigned char smem[LDS_TOTAL];
    unsigned short* Ks   = (unsigned short*)(smem + OFF_KBUF);
    float*          Vsf  = (float*)(smem + OFF_KBUF);
    float*          Ps_t = (float*)(smem + OFF_PST);
    unsigned short* Qs   = (unsigned short*)(smem + OFF_QS);
    float (*red)[4]      = (float(*)[4])(smem + OFF_RED);
    float* rowM          = (float*)(smem + OFF_RED + 512);
    float* rowSinv       = (float*)(smem + OFF_RED + 512 + 128);

    const int tid  = threadIdx.x;
    const int lane = tid & 63;
    const int w    = tid >> 6;         // wave 0..3
    const int lo   = lane & 31;
    const int hi   = lane >> 5;

    // XCD-aware swizzle: adjacent q-tiles on the same XCD
    const int wid = (blockIdx.x & 7) * 256 + (blockIdx.x >> 3);
    const int bh  = wid >> 6;          // 0..31
    const int qt  = wid & 63;          // 0..63
    const int i0  = qt * TQ;
    const int js0 = max(0, i0 - HALFW);
    const int jend = min(js0 + CT, Sc);

    const size_t rowbase = (size_t)bh * Sc;
    float* probsBase = probs + (rowbase + i0) * (size_t)Sc;

    // ---------- Phase Z: zero-fill probs outside [js0, jend) (nontemporal) ----------
    {
        const int headN = js0 & 3;                 // 0 or 2
        const int tailN = (4 - (jend & 3)) & 3;    // 0 or 2
        const int hn = headN + tailN;
        if (hn == 4) {
            int r = tid >> 2, s = tid & 3;
            if (r < TQ) {
                int col = (s < headN) ? (js0 - headN + s) : (jend + s - headN);
                __builtin_nontemporal_store(0.0f, probsBase + (size_t)r * Sc + col);
            }
        } else if (hn == 2) {
            int r = tid >> 1, s = tid & 1;
            if (r < TQ) {
                int col = (s < headN) ? (js0 - headN + s) : (jend + s - headN);
                __builtin_nontemporal_store(0.0f, probsBase + (size_t)r * Sc + col);
            }
        }
        const int leftQ   = (js0 - headN) >> 2;
        const int rightQ0 = (jend + tailN) >> 2;
        const fx4 z4 = {0.f, 0.f, 0.f, 0.f};
        for (int r = 0; r < TQ; ++r) {
            fx4* p4 = (fx4*)(probsBase + (size_t)r * Sc);
            for (int c = tid; c < leftQ; c += 256)
                __builtin_nontemporal_store(z4, p4 + c);
            for (int c = rightQ0 + tid; c < Sc / 4; c += 256)
                __builtin_nontemporal_store(z4, p4 + c);
        }
    }

    // ---------- Stage Q (bf16) ----------
    {
        const float4* Q4 = (const float4*)(Q + (rowbase + i0) * Dc);
        #pragma unroll
        for (int it = 0; it < 4; ++it) {
            int idx = tid + 256 * it;              // 0..1023
            int r = idx >> 5, d4 = idx & 31;
            float4 q4 = Q4[r * 32 + d4];
            ushort4 b;
            b.x = f2bf(q4.x); b.y = f2bf(q4.y); b.z = f2bf(q4.z); b.w = f2bf(q4.w);
            *(ushort4*)&Qs[r * KST + d4 * 4] = b;
        }
    }

    const float4* K4 = (const float4*)(K + rowbase * Dc);
    const float4* V4 = (const float4*)(V + rowbase * Dc);

    // ---------- Scores: 2 chunks of 128 K-rows; wave w does k-tile w per chunk ----------
    f32x16 accE[2];
    #pragma unroll
    for (int ch = 0; ch < 2; ++ch) {
        #pragma unroll
        for (int it = 0; it < 16; ++it) {
            int idx = tid + 256 * it;              // 0..4095
            int r = idx >> 5, d4 = idx & 31;
            int jn = js0 + ch * 128 + r;
            if (jn > Sc - 1) jn = Sc - 1;          // clamp; masked later
            float4 k4 = K4[(size_t)jn * 32 + d4];
            ushort4 b;
            b.x = f2bf(k4.x); b.y = f2bf(k4.y); b.z = f2bf(k4.z); b.w = f2bf(k4.w);
            *(ushort4*)&Ks[r * KST + d4 * 4] = b;
        }
        __syncthreads();
        f32x16 acc;
        #pragma unroll
        for (int i = 0; i < 16; ++i) acc[i] = 0.0f;
        const unsigned short* qrow = &Qs[lo * KST + hi * 8];
        const unsigned short* krow = &Ks[(w * 32 + lo) * KST + hi * 8];
        #pragma unroll
        for (int dk = 0; dk < 8; ++dk) {
            bf16x8 a = *(const bf16x8*)(qrow + dk * 16);
            bf16x8 b = *(const bf16x8*)(krow + dk * 16);
            acc = __builtin_amdgcn_mfma_f32_32x32x16_bf16(a, b, acc, 0, 0, 0);
        }
        accE[ch] = acc;
        __syncthreads();   // before Ks is overwritten
    }

    // ---------- Mask + scale, row-max ----------
    const int cg0 = js0 + w * 32 + lo;
    {
        float mred[16];
        #pragma unroll
        for (int i = 0; i < 16; ++i) {
            int rl = (i & 3) + 8 * (i >> 2) + 4 * hi;
            int rg = i0 + rl;
            float m = -3.0e38f;
            #pragma unroll
            for (int ch = 0; ch < 2; ++ch) {
                int cg = cg0 + ch * 128;
                bool valid = (cg < Sc) & (cg >= rg - HALFW) & (cg <= rg + HALFW);
                float sv = valid ? accE[ch][i] * SCALE : -3.0e38f;
                accE[ch][i] = sv;
                m = fmaxf(m, sv);
            }
            mred[i] = m;
        }
        #pragma unroll
        for (int mk = 1; mk < 32; mk <<= 1) {
            #pragma unroll
            for (int i = 0; i < 16; ++i)
                mred[i] = fmaxf(mred[i], __shfl_xor(mred[i], mk, 64));
        }
        if (lo == 0) {
            #pragma unroll
            for (int i = 0; i < 16; ++i) {
                int rl = (i & 3) + 8 * (i >> 2) + 4 * hi;
                red[rl][w] = mred[i];
            }
        }
    }
    __syncthreads();
    if (tid < 128) {
        int rr = tid >> 2, sl = tid & 3;
        float v = red[rr][sl];
        v = fmaxf(v, __shfl_xor(v, 1, 64));
        v = fmaxf(v, __shfl_xor(v, 2, 64));
        if (sl == 0) rowM[rr] = v;
    }
    __syncthreads();

    // ---------- exp + row-sum ----------
    {
        float sred[16];
        #pragma unroll
        for (int i = 0; i < 16; ++i) {
            int rl = (i & 3) + 8 * (i >> 2) + 4 * hi;
            float rm = rowM[rl];
            float e0 = __expf(accE[0][i] - rm);   // masked underflows to exact 0
            float e1 = __expf(accE[1][i] - rm);
            accE[0][i] = e0; accE[1][i] = e1;
            sred[i] = e0 + e1;
        }
        #pragma unroll
        for (int mk = 1; mk < 32; mk <<= 1) {
            #pragma unroll
            for (int i = 0; i < 16; ++i)
                sred[i] += __shfl_xor(sred[i], mk, 64);
        }
        if (lo == 0) {
            #pragma unroll
            for (int i = 0; i < 16; ++i) {
                int rl = (i & 3) + 8 * (i >> 2) + 4 * hi;
                red[rl][w] = sred[i];
            }
        }
    }
    __syncthreads();
    if (tid < 128) {
        int rr = tid >> 2, sl = tid & 3;
        float v = red[rr][sl];
        v += __shfl_xor(v, 1, 64);
        v += __shfl_xor(v, 2, 64);
        if (sl == 0) rowSinv[rr] = 1.0f / v;
    }
    __syncthreads();

    // ---------- probs: global in-window (NT); normalized p kept in accE ----------
    #pragma unroll
    for (int i = 0; i < 16; ++i) {
        int rl = (i & 3) + 8 * (i >> 2) + 4 * hi;
        float inv = rowSinv[rl];
        float* prow = probsBase + (size_t)rl * Sc;
        #pragma unroll
        for (int ch = 0; ch < 2; ++ch) {
            int cg = cg0 + ch * 128;
            float p = accE[ch][i] * inv;
            accE[ch][i] = p;                       // reuse as PV input
            if (cg < Sc) __builtin_nontemporal_store(p, prow + cg);
        }
    }

    // ---------- PV: 2 halves of 128 k; per half: Ps_t write + 2 chunks of 64 V-rows ----------
    // lane = rg(8: rows 4rg..4rg+3) x dgq(2: 16-float d-half) x kp(4: k%4)
    const int kp  = lane & 3;
    const int dgq = (lane >> 2) & 1;
    const int rg  = lane >> 3;
    fx4 o[4][4];
    #pragma unroll
    for (int c = 0; c < 4; ++c)
        #pragma unroll
        for (int j = 0; j < 4; ++j) o[c][j] = (fx4){0.f, 0.f, 0.f, 0.f};

    #pragma unroll
    for (int h = 0; h < 2; ++h) {
        // transposed P for this 128-k half: Ps_t[k_local][row], k_local = w*32+lo
        #pragma unroll
        for (int i = 0; i < 16; ++i) {
            int rl = (i & 3) + 8 * (i >> 2) + 4 * hi;
            Ps_t[(w * 32 + lo) * PTS + rl] = accE[h][i];
        }
        #pragma unroll
        for (int c2 = 0; c2 < 2; ++c2) {
            #pragma unroll
            for (int it = 0; it < 8; ++it) {
                int idx = tid + 256 * it;             // 0..2047
                int r = idx >> 5, d4 = idx & 31;
                int jn = js0 + h * 128 + c2 * 64 + r;
                if (jn > Sc - 1) jn = Sc - 1;         // p==0 there
                float4 v4g = V4[(size_t)jn * 32 + d4];
                *(float4*)&Vsf[r * VST + d4 * 4] = v4g;
            }
            __syncthreads();   // Ps_t (h) + Vsf (chunk) ready
            const float* Pbase = &Ps_t[(c2 * 64) * PTS + 4 * rg];
            const float* Vbase = &Vsf[w * 32 + dgq * 16];
            #pragma unroll 4
            for (int kk = 0; kk < 16; ++kk) {
                int k = 4 * kk + kp;
                fx4 p4 = *(const fx4*)(Pbase + k * PTS);   // rows 4rg..4rg+3 at col k
                const float* vr = Vbase + k * VST;
                fx4 v0 = *(const fx4*)(vr);
                fx4 v1 = *(const fx4*)(vr + 4);
                fx4 v2 = *(const fx4*)(vr + 8);
                fx4 v3 = *(const fx4*)(vr + 12);
                #pragma unroll
                for (int c = 0; c < 4; ++c) {
                    float pc = p4[c];
                    o[c][0] += v0 * pc;
                    o[c][1] += v1 * pc;
                    o[c][2] += v2 * pc;
                    o[c][3] += v3 * pc;
                }
            }
            __syncthreads();   // before Vsf / Ps_t overwritten
        }
    }

    // reduce over kp (lanes differing in bits 0..1) via shfl, then store
    #pragma unroll
    for (int c = 0; c < 4; ++c) {
        #pragma unroll
        for (int j = 0; j < 4; ++j) {
            fx4 t = o[c][j];
            #pragma unroll
            for (int comp = 0; comp < 4; ++comp) {
                float s = t[comp];
                s += __shfl_xor(s, 1, 64);
                s += __shfl_xor(s, 2, 64);
                t[comp] = s;
            }
            o[c][j] = t;
        }
    }
    if (kp == 0) {
        #pragma unroll
        for (int c = 0; c < 4; ++c) {
            float* crow = ctx + (rowbase + i0 + 4 * rg + c) * (size_t)Dc
                        + w * 32 + dgq * 16;
            #pragma unroll
            for (int j = 0; j < 4; ++j)
                __builtin_nontemporal_store(o[c][j], (fx4*)crow + j);
        }
    }
}

extern "C" void kernel_launch(void* const* d_in, const int* in_sizes, int n_in,
                              void* d_out, int out_size, void* d_ws, size_t ws_size,
                              hipStream_t stream) {
    const float* Q = (const float*)d_in[0];
    const float* K = (const float*)d_in[1];
    const float* V = (const float*)d_in[2];
    float* out   = (float*)d_out;
    float* ctx   = out;                                   // 2*16*2048*128
    float* probs = out + (size_t)2 * 16 * 2048 * 128;     // 2*16*2048*2048

    dim3 grid(2 * 16 * (Sc / TQ));   // 2048 blocks
    dim3 block(256);
    sparse_attn_mfma<<<grid, block, 0, stream>>>(Q, K, V, ctx, probs);
}

// Round 2
// 685.797 us; speedup vs baseline: 1.0047x; 1.0047x over previous
//
#include <hip/hip_runtime.h>
#include <math.h>

// SparseAttention B=2 H=16 S=2048 D=128, window half=102 (205 cols).
// out = ctx [B,H,S,D] ++ probs [B,H,S,S] (fp32).
// Round 5: zero-fill of out-of-window probs moved from kernel START to kernel
// END. Rationale: the first __syncthreads() lowers to s_waitcnt vmcnt(0) +
// s_barrier, and vmcnt counts the ~236 KB/block of zero-fill NT stores ->
// every block's first barrier drained them (~10 us/block exposed, all
// resident blocks stall together, which is why 2->3 blocks/CU was neutral).
// At the end of the kernel no barrier follows: stores drain across s_endpgm,
// overlapped with the next block's staging/MFMA on the same CU.

namespace {
constexpr int Sc = 2048, Dc = 128;
constexpr int HALFW = 102;
constexpr float SCALE = 0.08838834764831845f;   // 1/sqrt(128)
constexpr int TQ  = 32;    // q rows per block
constexpr int CT  = 256;   // padded window cols
constexpr int KST = 136;   // bf16 row stride for Qs/Ks
constexpr int VST = 132;   // fp32 row stride for Vsf (16B-aligned, kp-spread)
constexpr int PTS = 36;    // fp32 stride of Ps_t rows (per k): 32 rows + 4 pad
// LDS layout (bytes)
constexpr int OFF_KBUF = 0;                      // 34816: Ks bf16 128xKST / Vsf fp32 64xVST
constexpr int OFF_PST  = 34816;                  // 18432: Ps_t [128][36] fp32 (one 128-k half)
constexpr int OFF_QS   = 34816;                  // Qs bf16 32xKST overlay (dead before Ps_t)
constexpr int OFF_RED  = 34816 + 18432;          // red[32][4] + rowM[32] + rowSinv[32]
constexpr int LDS_TOTAL = OFF_RED + 512 + 128 + 128;   // 54016 B -> 3 blocks/CU
}

typedef __bf16 bf16x8 __attribute__((ext_vector_type(8)));
typedef float  f32x16 __attribute__((ext_vector_type(16)));
typedef float  fx4    __attribute__((ext_vector_type(4)));

__device__ __forceinline__ unsigned short f2bf(float f) {
    unsigned u = __float_as_uint(f);
    u += 0x7fffu + ((u >> 16) & 1u);     // round-to-nearest-even
    return (unsigned short)(u >> 16);
}

__global__ __launch_bounds__(256, 3) void sparse_attn_mfma(
    const float* __restrict__ Q, const float* __restrict__ K,
    const float* __restrict__ V, float* __restrict__ ctx,
    float* __restrict__ probs)
{
    __shared__ __align__(16) unsigned char smem[LDS_TOTAL];
    unsigned short* Ks   = (unsigned short*)(smem + OFF_KBUF);
    float*          Vsf  = (float*)(smem + OFF_KBUF);
    float*          Ps_t = (float*)(smem + OFF_PST);
    unsigned short* Qs   = (unsigned short*)(smem + OFF_QS);
    float (*red)[4]      = (float(*)[4])(smem + OFF_RED);
    float* rowM          = (float*)(smem + OFF_RED + 512);
    float* rowSinv       = (float*)(smem + OFF_RED + 512 + 128);

    const int tid  = threadIdx.x;
    const int lane = tid & 63;
    const int w    = tid >> 6;         // wave 0..3
    const int lo   = lane & 31;
    const int hi   = lane >> 5;

    // XCD-aware swizzle: adjacent q-tiles on the same XCD
    const int wid = (blockIdx.x & 7) * 256 + (blockIdx.x >> 3);
    const int bh  = wid >> 6;          // 0..31
    const int qt  = wid & 63;          // 0..63
    const int i0  = qt * TQ;
    const int js0 = max(0, i0 - HALFW);
    const int jend = min(js0 + CT, Sc);

    const size_t rowbase = (size_t)bh * Sc;
    float* probsBase = probs + (rowbase + i0) * (size_t)Sc;

    // ---------- Stage Q (bf16) ----------
    {
        const float4* Q4 = (const float4*)(Q + (rowbase + i0) * Dc);
        #pragma unroll
        for (int it = 0; it < 4; ++it) {
            int idx = tid + 256 * it;              // 0..1023
            int r = idx >> 5, d4 = idx & 31;
            float4 q4 = Q4[r * 32 + d4];
            ushort4 b;
            b.x = f2bf(q4.x); b.y = f2bf(q4.y); b.z = f2bf(q4.z); b.w = f2bf(q4.w);
            *(ushort4*)&Qs[r * KST + d4 * 4] = b;
        }
    }

    const float4* K4 = (const float4*)(K + rowbase * Dc);
    const float4* V4 = (const float4*)(V + rowbase * Dc);

    // ---------- Scores: 2 chunks of 128 K-rows; wave w does k-tile w per chunk ----------
    f32x16 accE[2];
    #pragma unroll
    for (int ch = 0; ch < 2; ++ch) {
        #pragma unroll
        for (int it = 0; it < 16; ++it) {
            int idx = tid + 256 * it;              // 0..4095
            int r = idx >> 5, d4 = idx & 31;
            int jn = js0 + ch * 128 + r;
            if (jn > Sc - 1) jn = Sc - 1;          // clamp; masked later
            float4 k4 = K4[(size_t)jn * 32 + d4];
            ushort4 b;
            b.x = f2bf(k4.x); b.y = f2bf(k4.y); b.z = f2bf(k4.z); b.w = f2bf(k4.w);
            *(ushort4*)&Ks[r * KST + d4 * 4] = b;
        }
        __syncthreads();
        f32x16 acc;
        #pragma unroll
        for (int i = 0; i < 16; ++i) acc[i] = 0.0f;
        const unsigned short* qrow = &Qs[lo * KST + hi * 8];
        const unsigned short* krow = &Ks[(w * 32 + lo) * KST + hi * 8];
        #pragma unroll
        for (int dk = 0; dk < 8; ++dk) {
            bf16x8 a = *(const bf16x8*)(qrow + dk * 16);
            bf16x8 b = *(const bf16x8*)(krow + dk * 16);
            acc = __builtin_amdgcn_mfma_f32_32x32x16_bf16(a, b, acc, 0, 0, 0);
        }
        accE[ch] = acc;
        __syncthreads();   // before Ks is overwritten
    }

    // ---------- Mask + scale, row-max ----------
    const int cg0 = js0 + w * 32 + lo;
    {
        float mred[16];
        #pragma unroll
        for (int i = 0; i < 16; ++i) {
            int rl = (i & 3) + 8 * (i >> 2) + 4 * hi;
            int rg = i0 + rl;
            float m = -3.0e38f;
            #pragma unroll
            for (int ch = 0; ch < 2; ++ch) {
                int cg = cg0 + ch * 128;
                bool valid = (cg < Sc) & (cg >= rg - HALFW) & (cg <= rg + HALFW);
                float sv = valid ? accE[ch][i] * SCALE : -3.0e38f;
                accE[ch][i] = sv;
                m = fmaxf(m, sv);
            }
            mred[i] = m;
        }
        #pragma unroll
        for (int mk = 1; mk < 32; mk <<= 1) {
            #pragma unroll
            for (int i = 0; i < 16; ++i)
                mred[i] = fmaxf(mred[i], __shfl_xor(mred[i], mk, 64));
        }
        if (lo == 0) {
            #pragma unroll
            for (int i = 0; i < 16; ++i) {
                int rl = (i & 3) + 8 * (i >> 2) + 4 * hi;
                red[rl][w] = mred[i];
            }
        }
    }
    __syncthreads();
    if (tid < 128) {
        int rr = tid >> 2, sl = tid & 3;
        float v = red[rr][sl];
        v = fmaxf(v, __shfl_xor(v, 1, 64));
        v = fmaxf(v, __shfl_xor(v, 2, 64));
        if (sl == 0) rowM[rr] = v;
    }
    __syncthreads();

    // ---------- exp + row-sum ----------
    {
        float sred[16];
        #pragma unroll
        for (int i = 0; i < 16; ++i) {
            int rl = (i & 3) + 8 * (i >> 2) + 4 * hi;
            float rm = rowM[rl];
            float e0 = __expf(accE[0][i] - rm);   // masked underflows to exact 0
            float e1 = __expf(accE[1][i] - rm);
            accE[0][i] = e0; accE[1][i] = e1;
            sred[i] = e0 + e1;
        }
        #pragma unroll
        for (int mk = 1; mk < 32; mk <<= 1) {
            #pragma unroll
            for (int i = 0; i < 16; ++i)
                sred[i] += __shfl_xor(sred[i], mk, 64);
        }
        if (lo == 0) {
            #pragma unroll
            for (int i = 0; i < 16; ++i) {
                int rl = (i & 3) + 8 * (i >> 2) + 4 * hi;
                red[rl][w] = sred[i];
            }
        }
    }
    __syncthreads();
    if (tid < 128) {
        int rr = tid >> 2, sl = tid & 3;
        float v = red[rr][sl];
        v += __shfl_xor(v, 1, 64);
        v += __shfl_xor(v, 2, 64);
        if (sl == 0) rowSinv[rr] = 1.0f / v;
    }
    __syncthreads();

    // ---------- probs: global in-window (NT); normalized p kept in accE ----------
    #pragma unroll
    for (int i = 0; i < 16; ++i) {
        int rl = (i & 3) + 8 * (i >> 2) + 4 * hi;
        float inv = rowSinv[rl];
        float* prow = probsBase + (size_t)rl * Sc;
        #pragma unroll
        for (int ch = 0; ch < 2; ++ch) {
            int cg = cg0 + ch * 128;
            float p = accE[ch][i] * inv;
            accE[ch][i] = p;                       // reuse as PV input
            if (cg < Sc) __builtin_nontemporal_store(p, prow + cg);
        }
    }

    // ---------- PV: 2 halves of 128 k; per half: Ps_t write + 2 chunks of 64 V-rows ----------
    // lane = rg(8: rows 4rg..4rg+3) x dgq(2: 16-float d-half) x kp(4: k%4)
    const int kp  = lane & 3;
    const int dgq = (lane >> 2) & 1;
    const int rg  = lane >> 3;
    fx4 o[4][4];
    #pragma unroll
    for (int c = 0; c < 4; ++c)
        #pragma unroll
        for (int j = 0; j < 4; ++j) o[c][j] = (fx4){0.f, 0.f, 0.f, 0.f};

    #pragma unroll
    for (int h = 0; h < 2; ++h) {
        // transposed P for this 128-k half: Ps_t[k_local][row], k_local = w*32+lo
        #pragma unroll
        for (int i = 0; i < 16; ++i) {
            int rl = (i & 3) + 8 * (i >> 2) + 4 * hi;
            Ps_t[(w * 32 + lo) * PTS + rl] = accE[h][i];
        }
        #pragma unroll
        for (int c2 = 0; c2 < 2; ++c2) {
            #pragma unroll
            for (int it = 0; it < 8; ++it) {
                int idx = tid + 256 * it;             // 0..2047
                int r = idx >> 5, d4 = idx & 31;
                int jn = js0 + h * 128 + c2 * 64 + r;
                if (jn > Sc - 1) jn = Sc - 1;         // p==0 there
                float4 v4g = V4[(size_t)jn * 32 + d4];
                *(float4*)&Vsf[r * VST + d4 * 4] = v4g;
            }
            __syncthreads();   // Ps_t (h) + Vsf (chunk) ready
            const float* Pbase = &Ps_t[(c2 * 64) * PTS + 4 * rg];
            const float* Vbase = &Vsf[w * 32 + dgq * 16];
            #pragma unroll 4
            for (int kk = 0; kk < 16; ++kk) {
                int k = 4 * kk + kp;
                fx4 p4 = *(const fx4*)(Pbase + k * PTS);   // rows 4rg..4rg+3 at col k
                const float* vr = Vbase + k * VST;
                fx4 v0 = *(const fx4*)(vr);
                fx4 v1 = *(const fx4*)(vr + 4);
                fx4 v2 = *(const fx4*)(vr + 8);
                fx4 v3 = *(const fx4*)(vr + 12);
                #pragma unroll
                for (int c = 0; c < 4; ++c) {
                    float pc = p4[c];
                    o[c][0] += v0 * pc;
                    o[c][1] += v1 * pc;
                    o[c][2] += v2 * pc;
                    o[c][3] += v3 * pc;
                }
            }
            __syncthreads();   // before Vsf / Ps_t overwritten
        }
    }

    // reduce over kp (lanes differing in bits 0..1) via shfl, then store
    #pragma unroll
    for (int c = 0; c < 4; ++c) {
        #pragma unroll
        for (int j = 0; j < 4; ++j) {
            fx4 t = o[c][j];
            #pragma unroll
            for (int comp = 0; comp < 4; ++comp) {
                float s = t[comp];
                s += __shfl_xor(s, 1, 64);
                s += __shfl_xor(s, 2, 64);
                t[comp] = s;
            }
            o[c][j] = t;
        }
    }
    if (kp == 0) {
        #pragma unroll
        for (int c = 0; c < 4; ++c) {
            float* crow = ctx + (rowbase + i0 + 4 * rg + c) * (size_t)Dc
                        + w * 32 + dgq * 16;
            #pragma unroll
            for (int j = 0; j < 4; ++j)
                __builtin_nontemporal_store(o[c][j], (fx4*)crow + j);
        }
    }

    // ---------- Phase Z (moved to END): zero-fill probs outside [js0, jend) ----------
    // No barrier follows these stores: they drain across s_endpgm, overlapped
    // with the next block's staging/MFMA on this CU.
    {
        const int headN = js0 & 3;                 // 0 or 2
        const int tailN = (4 - (jend & 3)) & 3;    // 0 or 2
        const int hn = headN + tailN;
        if (hn == 4) {
            int r = tid >> 2, s = tid & 3;
            if (r < TQ) {
                int col = (s < headN) ? (js0 - headN + s) : (jend + s - headN);
                __builtin_nontemporal_store(0.0f, probsBase + (size_t)r * Sc + col);
            }
        } else if (hn == 2) {
            int r = tid >> 1, s = tid & 1;
            if (r < TQ) {
                int col = (s < headN) ? (js0 - headN + s) : (jend + s - headN);
                __builtin_nontemporal_store(0.0f, probsBase + (size_t)r * Sc + col);
            }
        }
        const int leftQ   = (js0 - headN) >> 2;
        const int rightQ0 = (jend + tailN) >> 2;
        const fx4 z4 = {0.f, 0.f, 0.f, 0.f};
        for (int r = 0; r < TQ; ++r) {
            fx4* p4 = (fx4*)(probsBase + (size_t)r * Sc);
            for (int c = tid; c < leftQ; c += 256)
                __builtin_nontemporal_store(z4, p4 + c);
            for (int c = rightQ0 + tid; c < Sc / 4; c += 256)
                __builtin_nontemporal_store(z4, p4 + c);
        }
    }
}

extern "C" void kernel_launch(void* const* d_in, const int* in_sizes, int n_in,
                              void* d_out, int out_size, void* d_ws, size_t ws_size,
                              hipStream_t stream) {
    const float* Q = (const float*)d_in[0];
    const float* K = (const float*)d_in[1];
    const float* V = (const float*)d_in[2];
    float* out   = (float*)d_out;
    float* ctx   = out;                                   // 2*16*2048*128
    float* probs = out + (size_t)2 * 16 * 2048 * 128;     // 2*16*2048*2048

    dim3 grid(2 * 16 * (Sc / TQ));   // 2048 blocks
    dim3 block(256);
    sparse_attn_mfma<<<grid, block, 0, stream>>>(Q, K, V, ctx, probs);
}

// Round 3
// 681.958 us; speedup vs baseline: 1.0104x; 1.0056x over previous
//
#include <hip/hip_runtime.h>
#include <math.h>

// SparseAttention B=2 H=16 S=2048 D=128, window half=102 (205 cols).
// out = ctx [B,H,S,D] ++ probs [B,H,S,S] (fp32).
// Round 6: PV moved from scalar-VALU (4096 FMA + 320 ds_read_b128 per wave)
// to MFMA (16 x mfma_f32_32x32x16_bf16 + 32 ds_read_b128 per wave).
//  - P stored to LDS as bf16 [q=32][k=256], A-operand layout, XOR-swizzled.
//  - V staged as bf16 TRANSPOSED [d=128][k=128] per 128-k chunk (register
//    transpose in staging: each thread loads 4k x 4d, writes 4 ds_write_b64).
//  - All LDS tiles XOR-swizzled (bits 4-6 of byte addr by row group): the
//    old Ks/Qs reads were ~8-way bank conflicted (row stride 272B, rows 8
//    apart alias the same 128B bank window). Swizzle is bijective: used row
//    width <= 256B < stride, write and read apply the identical map.
//  - kp shfl-reduce and o[4][4] accumulator eliminated (wave owns full k-sum
//    for its 32-d block); ctx stored straight from MFMA C-layout.
// probs numerics identical to round 5; ctx adds ~2e-3 bf16-P/V rounding,
// below the probs-driven absmax 0.0078125.

namespace {
constexpr int Sc = 2048, Dc = 128;
constexpr int HALFW = 102;
constexpr float SCALE = 0.08838834764831845f;   // 1/sqrt(128)
constexpr int TQ  = 32;    // q rows per block
constexpr int CT  = 256;   // padded window cols
constexpr int KSB = 272;   // byte stride of Qs/Ks/Vt rows (136 bf16)
constexpr int PSB = 512;   // byte stride of Ps rows (256 bf16, 128B multiple)
// LDS layout (bytes)
constexpr int OFF_KBUF = 0;              // 34816: Ks bf16 128x272B | Vt bf16 128x272B
constexpr int OFF_PS   = 34816;          // 16384: Ps bf16 [32][256] swizzled
constexpr int OFF_QS   = 34816;          // Qs bf16 32x272B overlay (dead before Ps)
constexpr int OFF_RED  = 34816 + 16384;  // red[32][4] + rowM[32] + rowSinv[32]
constexpr int LDS_TOTAL = OFF_RED + 512 + 128 + 128;   // 51968 -> 3 blocks/CU
}

typedef __bf16 bf16x8 __attribute__((ext_vector_type(8)));
typedef float  f32x16 __attribute__((ext_vector_type(16)));
typedef float  fx4    __attribute__((ext_vector_type(4)));

__device__ __forceinline__ unsigned short f2bf(float f) {
    unsigned u = __float_as_uint(f);
    u += 0x7fffu + ((u >> 16) & 1u);     // round-to-nearest-even
    return (unsigned short)(u >> 16);
}

__global__ __launch_bounds__(256, 3) void sparse_attn_mfma(
    const float* __restrict__ Q, const float* __restrict__ K,
    const float* __restrict__ V, float* __restrict__ ctx,
    float* __restrict__ probs)
{
    __shared__ __align__(16) unsigned char smem[LDS_TOTAL];
    float (*red)[4]      = (float(*)[4])(smem + OFF_RED);
    float* rowM          = (float*)(smem + OFF_RED + 512);
    float* rowSinv       = (float*)(smem + OFF_RED + 512 + 128);

    const int tid  = threadIdx.x;
    const int lane = tid & 63;
    const int w    = tid >> 6;         // wave 0..3
    const int lo   = lane & 31;
    const int hi   = lane >> 5;

    // XCD-aware swizzle: adjacent q-tiles on the same XCD
    const int wid = (blockIdx.x & 7) * 256 + (blockIdx.x >> 3);
    const int bh  = wid >> 6;          // 0..31
    const int qt  = wid & 63;          // 0..63
    const int i0  = qt * TQ;
    const int js0 = max(0, i0 - HALFW);
    const int jend = min(js0 + CT, Sc);

    const size_t rowbase = (size_t)bh * Sc;
    float* probsBase = probs + (rowbase + i0) * (size_t)Sc;

    // ---------- Stage Q (bf16, swizzled) ----------
    {
        const float4* Q4 = (const float4*)(Q + (rowbase + i0) * Dc);
        #pragma unroll
        for (int it = 0; it < 4; ++it) {
            int idx = tid + 256 * it;              // 0..1023
            int r = idx >> 5, d4 = idx & 31;
            float4 q4 = Q4[r * 32 + d4];
            ushort4 b;
            b.x = f2bf(q4.x); b.y = f2bf(q4.y); b.z = f2bf(q4.z); b.w = f2bf(q4.w);
            *(ushort4*)(smem + OFF_QS + ((r * KSB + d4 * 8) ^ ((r >> 3) << 4))) = b;
        }
    }

    const float4* K4 = (const float4*)(K + rowbase * Dc);
    const float4* V4 = (const float4*)(V + rowbase * Dc);

    // V stage helper: 128 k-rows -> Vt bf16 [d=128][k=128], transposed, swizzled.
    auto stageV = [&](int h) {
        const int dq  = tid & 31;       // d quad index: d = 4*dq + m
        const int kb8 = tid >> 5;       // 0..7
        const int kbase = js0 + 128 * h;
        #pragma unroll
        for (int s = 0; s < 4; ++s) {
            int kb = kb8 + 8 * s;       // 0..31 (4-row k-block)
            int k4 = kbase + kb * 4;
            float4 a0 = V4[(size_t)min(k4 + 0, Sc - 1) * 32 + dq];
            float4 a1 = V4[(size_t)min(k4 + 1, Sc - 1) * 32 + dq];
            float4 a2 = V4[(size_t)min(k4 + 2, Sc - 1) * 32 + dq];
            float4 a3 = V4[(size_t)min(k4 + 3, Sc - 1) * 32 + dq];
            const float* f0 = (const float*)&a0;
            const float* f1 = (const float*)&a1;
            const float* f2 = (const float*)&a2;
            const float* f3 = (const float*)&a3;
            #pragma unroll
            for (int m = 0; m < 4; ++m) {
                ushort4 bb;
                bb.x = f2bf(f0[m]); bb.y = f2bf(f1[m]);
                bb.z = f2bf(f2[m]); bb.w = f2bf(f3[m]);
                int d = 4 * dq + m;
                *(ushort4*)(smem + OFF_KBUF +
                            ((d * KSB + 8 * kb) ^ (((d >> 3) & 7) << 4))) = bb;
            }
        }
    };

    // ---------- Scores: 2 chunks of 128 K-rows; wave w does k-tile w per chunk ----------
    f32x16 accE[2];
    {
        const int qswz = (lo >> 3) << 4;
        const int rk   = w * 32 + lo;
        const int kswz = ((rk >> 3) & 7) << 4;
        #pragma unroll
        for (int ch = 0; ch < 2; ++ch) {
            #pragma unroll
            for (int it = 0; it < 16; ++it) {
                int idx = tid + 256 * it;              // 0..4095
                int r = idx >> 5, d4 = idx & 31;
                int jn = js0 + ch * 128 + r;
                if (jn > Sc - 1) jn = Sc - 1;          // clamp; masked later
                float4 k4 = K4[(size_t)jn * 32 + d4];
                ushort4 b;
                b.x = f2bf(k4.x); b.y = f2bf(k4.y); b.z = f2bf(k4.z); b.w = f2bf(k4.w);
                *(ushort4*)(smem + OFF_KBUF +
                            ((r * KSB + d4 * 8) ^ (((r >> 3) & 7) << 4))) = b;
            }
            __syncthreads();
            f32x16 acc;
            #pragma unroll
            for (int i = 0; i < 16; ++i) acc[i] = 0.0f;
            #pragma unroll
            for (int dk = 0; dk < 8; ++dk) {
                bf16x8 a = *(const bf16x8*)(smem + OFF_QS +
                            ((lo * KSB + hi * 16 + dk * 32) ^ qswz));
                bf16x8 b = *(const bf16x8*)(smem + OFF_KBUF +
                            ((rk * KSB + hi * 16 + dk * 32) ^ kswz));
                acc = __builtin_amdgcn_mfma_f32_32x32x16_bf16(a, b, acc, 0, 0, 0);
            }
            accE[ch] = acc;
            __syncthreads();   // before Ks is overwritten
        }
    }

    // ---------- V chunk 0 staging (Ks dead; overlaps softmax across waves) ----------
    stageV(0);

    // ---------- Mask + scale, row-max ----------
    const int cg0 = js0 + w * 32 + lo;
    {
        float mred[16];
        #pragma unroll
        for (int i = 0; i < 16; ++i) {
            int rl = (i & 3) + 8 * (i >> 2) + 4 * hi;
            int rg = i0 + rl;
            float m = -3.0e38f;
            #pragma unroll
            for (int ch = 0; ch < 2; ++ch) {
                int cg = cg0 + ch * 128;
                bool valid = (cg < Sc) & (cg >= rg - HALFW) & (cg <= rg + HALFW);
                float sv = valid ? accE[ch][i] * SCALE : -3.0e38f;
                accE[ch][i] = sv;
                m = fmaxf(m, sv);
            }
            mred[i] = m;
        }
        #pragma unroll
        for (int mk = 1; mk < 32; mk <<= 1) {
            #pragma unroll
            for (int i = 0; i < 16; ++i)
                mred[i] = fmaxf(mred[i], __shfl_xor(mred[i], mk, 64));
        }
        if (lo == 0) {
            #pragma unroll
            for (int i = 0; i < 16; ++i) {
                int rl = (i & 3) + 8 * (i >> 2) + 4 * hi;
                red[rl][w] = mred[i];
            }
        }
    }
    __syncthreads();
    if (tid < 128) {
        int rr = tid >> 2, sl = tid & 3;
        float v = red[rr][sl];
        v = fmaxf(v, __shfl_xor(v, 1, 64));
        v = fmaxf(v, __shfl_xor(v, 2, 64));
        if (sl == 0) rowM[rr] = v;
    }
    __syncthreads();

    // ---------- exp + row-sum ----------
    {
        float sred[16];
        #pragma unroll
        for (int i = 0; i < 16; ++i) {
            int rl = (i & 3) + 8 * (i >> 2) + 4 * hi;
            float rm = rowM[rl];
            float e0 = __expf(accE[0][i] - rm);   // masked underflows to exact 0
            float e1 = __expf(accE[1][i] - rm);
            accE[0][i] = e0; accE[1][i] = e1;
            sred[i] = e0 + e1;
        }
        #pragma unroll
        for (int mk = 1; mk < 32; mk <<= 1) {
            #pragma unroll
            for (int i = 0; i < 16; ++i)
                sred[i] += __shfl_xor(sred[i], mk, 64);
        }
        if (lo == 0) {
            #pragma unroll
            for (int i = 0; i < 16; ++i) {
                int rl = (i & 3) + 8 * (i >> 2) + 4 * hi;
                red[rl][w] = sred[i];
            }
        }
    }
    __syncthreads();
    if (tid < 128) {
        int rr = tid >> 2, sl = tid & 3;
        float v = red[rr][sl];
        v += __shfl_xor(v, 1, 64);
        v += __shfl_xor(v, 2, 64);
        if (sl == 0) rowSinv[rr] = 1.0f / v;
    }
    __syncthreads();

    // ---------- probs: global in-window (NT) + Ps bf16 [q][k] (A-operand layout) ----------
    #pragma unroll
    for (int i = 0; i < 16; ++i) {
        int rl = (i & 3) + 8 * (i >> 2) + 4 * hi;
        float inv = rowSinv[rl];
        float* prow = probsBase + (size_t)rl * Sc;
        #pragma unroll
        for (int ch = 0; ch < 2; ++ch) {
            int cg = cg0 + ch * 128;
            float p = accE[ch][i] * inv;
            int kix = cg - js0;                    // 0..255 always
            *(unsigned short*)(smem + OFF_PS +
                ((rl * PSB + 2 * kix) ^ ((rl & 7) << 4))) = f2bf(p);
            if (cg < Sc) __builtin_nontemporal_store(p, prow + cg);
        }
    }
    __syncthreads();   // Ps + Vt chunk 0 visible

    // ---------- PV via MFMA: wave w owns d-block [32w, 32w+32) ----------
    f32x16 oacc;
    #pragma unroll
    for (int i = 0; i < 16; ++i) oacc[i] = 0.0f;
    const int dloc = 32 * w + lo;
    const int vswz = ((dloc >> 3) & 7) << 4;
    const int pswz = (lo & 7) << 4;

    #pragma unroll
    for (int ks = 0; ks < 8; ++ks) {               // chunk 0: k 0..127
        bf16x8 pa = *(const bf16x8*)(smem + OFF_PS +
                    ((lo * PSB + 32 * ks + 16 * hi) ^ pswz));
        bf16x8 vb = *(const bf16x8*)(smem + OFF_KBUF +
                    ((dloc * KSB + 32 * ks + 16 * hi) ^ vswz));
        oacc = __builtin_amdgcn_mfma_f32_32x32x16_bf16(pa, vb, oacc, 0, 0, 0);
    }
    __syncthreads();   // PV0 reads done before Vt overwritten
    stageV(1);
    __syncthreads();   // Vt chunk 1 visible
    #pragma unroll
    for (int ks = 0; ks < 8; ++ks) {               // chunk 1: k 128..255
        bf16x8 pa = *(const bf16x8*)(smem + OFF_PS +
                    ((lo * PSB + 256 + 32 * ks + 16 * hi) ^ pswz));
        bf16x8 vb = *(const bf16x8*)(smem + OFF_KBUF +
                    ((dloc * KSB + 32 * ks + 16 * hi) ^ vswz));
        oacc = __builtin_amdgcn_mfma_f32_32x32x16_bf16(pa, vb, oacc, 0, 0, 0);
    }

    // ---------- ctx store straight from MFMA C-layout ----------
    #pragma unroll
    for (int i = 0; i < 16; ++i) {
        int rl = (i & 3) + 8 * (i >> 2) + 4 * hi;
        __builtin_nontemporal_store(oacc[i],
            ctx + (rowbase + i0 + rl) * (size_t)Dc + dloc);
    }

    // ---------- Phase Z (END): zero-fill probs outside [js0, jend) ----------
    {
        const int headN = js0 & 3;                 // 0 or 2
        const int tailN = (4 - (jend & 3)) & 3;    // 0 or 2
        const int hn = headN + tailN;
        if (hn == 4) {
            int r = tid >> 2, s = tid & 3;
            if (r < TQ) {
                int col = (s < headN) ? (js0 - headN + s) : (jend + s - headN);
                __builtin_nontemporal_store(0.0f, probsBase + (size_t)r * Sc + col);
            }
        } else if (hn == 2) {
            int r = tid >> 1, s = tid & 1;
            if (r < TQ) {
                int col = (s < headN) ? (js0 - headN + s) : (jend + s - headN);
                __builtin_nontemporal_store(0.0f, probsBase + (size_t)r * Sc + col);
            }
        }
        const int leftQ   = (js0 - headN) >> 2;
        const int rightQ0 = (jend + tailN) >> 2;
        const fx4 z4 = {0.f, 0.f, 0.f, 0.f};
        for (int r = 0; r < TQ; ++r) {
            fx4* p4 = (fx4*)(probsBase + (size_t)r * Sc);
            for (int c = tid; c < leftQ; c += 256)
                __builtin_nontemporal_store(z4, p4 + c);
            for (int c = rightQ0 + tid; c < Sc / 4; c += 256)
                __builtin_nontemporal_store(z4, p4 + c);
        }
    }
}

extern "C" void kernel_launch(void* const* d_in, const int* in_sizes, int n_in,
                              void* d_out, int out_size, void* d_ws, size_t ws_size,
                              hipStream_t stream) {
    const float* Q = (const float*)d_in[0];
    const float* K = (const float*)d_in[1];
    const float* V = (const float*)d_in[2];
    float* out   = (float*)d_out;
    float* ctx   = out;                                   // 2*16*2048*128
    float* probs = out + (size_t)2 * 16 * 2048 * 128;     // 2*16*2048*2048

    dim3 grid(2 * 16 * (Sc / TQ));   // 2048 blocks
    dim3 block(256);
    sparse_attn_mfma<<<grid, block, 0, stream>>>(Q, K, V, ctx, probs);
}